// Round 10
// baseline (268.476 us; speedup 1.0000x reference)
//
#include <hip/hip_runtime.h>
#include <hip/hip_bf16.h>
#include <math.h>

#define NN 50000
#define EE 500000
#define ETOT (EE + NN)
#define NG 64

typedef __attribute__((ext_vector_type(8))) short short8v;   // 8 bf16 (4 VGPRs)
typedef __attribute__((ext_vector_type(4))) float float4v;   // 4 fp32 acc
typedef __attribute__((ext_vector_type(2))) float float2v;

__device__ __forceinline__ float bf2f(unsigned short u) {
    unsigned int v = ((unsigned int)u) << 16;
    return __builtin_bit_cast(float, v);
}
__device__ __forceinline__ unsigned short f2bf(float f) {
    __hip_bfloat16 h = __float2bfloat16(f);
    return *(unsigned short*)&h;
}
// hardware fp8 e4m3 converts (gfx950 native)
__device__ __forceinline__ unsigned char f2fp8_hw(float f) {
    return (unsigned char)(__builtin_amdgcn_cvt_pk_fp8_f32(f, f, 0, false) & 0xff);
}

// ---------------- histogram of dst + per-graph node counts ----------------
__global__ void k_hist(const int* __restrict__ ei, const int* __restrict__ batch,
                       int* __restrict__ counts, int* __restrict__ gcount) {
    int t = blockIdx.x * 256 + threadIdx.x;
    if (t < ETOT) {
        int dst = (t < EE) ? ei[EE + t] : (t - EE);
        atomicAdd(counts + dst, 1);
    }
    if (t < NN) {
        int g = batch[t];
        int g0 = __shfl(g, 0);
        bool same = (g == g0);
        unsigned long long m = __ballot(same);
        if (same) {
            if ((threadIdx.x & 63) == (__ffsll((long long)m) - 1))
                atomicAdd(gcount + g0, (int)__popcll(m));
        } else {
            atomicAdd(gcount + g, 1);
        }
    }
}

// ---------------- exclusive scan counts -> indptr (+ seed cursor) ---------
// 4 elements per thread (int4), 13 chunk iterations.
__global__ void k_scan(const int* __restrict__ counts, int* __restrict__ indptr,
                       int* __restrict__ cursor) {
    __shared__ int wsum[16];
    __shared__ int carry_s;
    int tid = threadIdx.x;
    int lane = tid & 63;
    int w = tid >> 6;
    if (tid == 0) carry_s = 0;
    __syncthreads();
    for (int base = 0; base < NN; base += 4096) {
        int i = base + tid * 4;
        int v0 = 0, v1 = 0, v2 = 0, v3 = 0;
        if (i + 3 < NN) {
            int4 vv = *(const int4*)&counts[i];
            v0 = vv.x; v1 = vv.y; v2 = vv.z; v3 = vv.w;
        } else {
            if (i < NN) v0 = counts[i];
            if (i + 1 < NN) v1 = counts[i + 1];
            if (i + 2 < NN) v2 = counts[i + 2];
            if (i + 3 < NN) v3 = counts[i + 3];
        }
        int tot = v0 + v1 + v2 + v3;
        int s = tot;
#pragma unroll
        for (int off = 1; off < 64; off <<= 1) {
            int u = __shfl_up(s, off);
            if (lane >= off) s += u;
        }
        if (lane == 63) wsum[w] = s;
        __syncthreads();
        if (w == 0) {
            int t2 = (lane < 16) ? wsum[lane] : 0;
#pragma unroll
            for (int off = 1; off < 16; off <<= 1) {
                int u = __shfl_up(t2, off);
                if (lane >= off) t2 += u;
            }
            if (lane < 16) wsum[lane] = t2;
        }
        __syncthreads();
        int wpre = (w == 0) ? 0 : wsum[w - 1];
        int incl = s + wpre;
        int carry = carry_s;
        int e = carry + incl - tot;
        if (i < NN)     { indptr[i] = e;                cursor[i] = e; }
        if (i + 1 < NN) { int q = e + v0;               indptr[i+1] = q; cursor[i+1] = q; }
        if (i + 2 < NN) { int q = e + v0 + v1;          indptr[i+2] = q; cursor[i+2] = q; }
        if (i + 3 < NN) { int q = e + v0 + v1 + v2;     indptr[i+3] = q; cursor[i+3] = q; }
        __syncthreads();
        if (tid == 1023) carry_s = carry + incl;
        __syncthreads();
    }
    if (tid == 0) indptr[NN] = carry_s;
}

// ---------------- W1 -> split bf16 (hi + residual) ------------------------
__global__ void k_cvtw(const float* __restrict__ W1, unsigned short* __restrict__ whi,
                       unsigned short* __restrict__ wlo) {
    int t = blockIdx.x * 256 + threadIdx.x;
    if (t >= 256 * 128) return;
    float v = W1[t];
    __hip_bfloat16 h = __float2bfloat16(v);
    float hf = __bfloat162float(h);
    __hip_bfloat16 r = __float2bfloat16(v - hf);
    whi[t] = *(unsigned short*)&h;
    wlo[t] = *(unsigned short*)&r;
}

// ---------------- x -> split bf16 (hi + residual), 8 elems/thread ---------
__global__ void k_cvtx(const float* __restrict__ x, unsigned short* __restrict__ xh,
                       unsigned short* __restrict__ xl) {
    int t = blockIdx.x * 256 + threadIdx.x;
    if (t >= NN * 128 / 8) return;
    float4 a = *(const float4*)&x[(size_t)t * 8];
    float4 b = *(const float4*)&x[(size_t)t * 8 + 4];
    float f[8] = {a.x, a.y, a.z, a.w, b.x, b.y, b.z, b.w};
    short8v vh, vl;
#pragma unroll
    for (int j = 0; j < 8; ++j) {
        __hip_bfloat16 h = __float2bfloat16(f[j]);
        float hf = __bfloat162float(h);
        __hip_bfloat16 r = __float2bfloat16(f[j] - hf);
        vh[j] = *(short*)&h;
        vl[j] = *(short*)&r;
    }
    *(short8v*)&xh[(size_t)t * 8] = vh;
    *(short8v*)&xl[(size_t)t * 8] = vl;
}

// ---------------- GEMM1 via split-bf16 MFMA + fused alpha logits ----------
// h = x @ W1^T; emits fp8 h1f8 (gather payload) + alpha_s/alpha_d (fp32).
// Wave w covers cols [w*64,(w+1)*64) = head w; rows [bm0,bm0+32).
// A/B frags: 16-index = lane&15, k = (lane>>4)*8+j. D: col=lane&15,
// row=(lane>>4)*4+reg.
__global__ __launch_bounds__(256) void k_gemm1(const unsigned short* __restrict__ xh,
                                               const unsigned short* __restrict__ xl,
                                               const unsigned short* __restrict__ whi,
                                               const unsigned short* __restrict__ wlo,
                                               const float* __restrict__ att_s,
                                               const float* __restrict__ att_d,
                                               unsigned char* __restrict__ h1f8,
                                               float* __restrict__ alpha_s,
                                               float* __restrict__ alpha_d) {
    int w = threadIdx.x >> 6;
    int l = threadIdx.x & 63;
    int bm0 = blockIdx.x * 32;
    int i16 = l & 15;
    int kb = (l >> 4) * 8;
    int colb = w * 64;

    float4v acc[2][4];
#pragma unroll
    for (int mi = 0; mi < 2; ++mi)
#pragma unroll
        for (int ni = 0; ni < 4; ++ni)
            acc[mi][ni] = (float4v){0.f, 0.f, 0.f, 0.f};

    for (int k0 = 0; k0 < 128; k0 += 32) {
        short8v ah[2], alo[2];
#pragma unroll
        for (int mi = 0; mi < 2; ++mi) {
            int r = bm0 + mi * 16 + i16;
            if (r < NN) {
                ah[mi]  = *(const short8v*)&xh[(size_t)r * 128 + k0 + kb];
                alo[mi] = *(const short8v*)&xl[(size_t)r * 128 + k0 + kb];
            } else {
                ah[mi] = (short8v){0,0,0,0,0,0,0,0};
                alo[mi] = (short8v){0,0,0,0,0,0,0,0};
            }
        }
#pragma unroll
        for (int ni = 0; ni < 4; ++ni) {
            size_t widx = (size_t)(colb + ni * 16 + i16) * 128 + k0 + kb;
            short8v bh = *(const short8v*)&whi[widx];
            short8v bl = *(const short8v*)&wlo[widx];
#pragma unroll
            for (int mi = 0; mi < 2; ++mi) {
                acc[mi][ni] = __builtin_amdgcn_mfma_f32_16x16x32_bf16(ah[mi], bh, acc[mi][ni], 0, 0, 0);
                acc[mi][ni] = __builtin_amdgcn_mfma_f32_16x16x32_bf16(ah[mi], bl, acc[mi][ni], 0, 0, 0);
                acc[mi][ni] = __builtin_amdgcn_mfma_f32_16x16x32_bf16(alo[mi], bh, acc[mi][ni], 0, 0, 0);
            }
        }
    }
    // epilogue: fp8 store + fused alpha logits (head = w)
    int drb = (l >> 4) * 4;
    int dc = l & 15;
    float asw[4], adw[4];
#pragma unroll
    for (int ni = 0; ni < 4; ++ni) {
        asw[ni] = att_s[colb + ni * 16 + dc];
        adw[ni] = att_d[colb + ni * 16 + dc];
    }
#pragma unroll
    for (int mi = 0; mi < 2; ++mi) {
#pragma unroll
        for (int r = 0; r < 4; ++r) {
            int row = bm0 + mi * 16 + drb + r;
            float s = 0.f, d = 0.f;
#pragma unroll
            for (int ni = 0; ni < 4; ++ni) {
                float v = acc[mi][ni][r];
                s += v * asw[ni];
                d += v * adw[ni];
                if (row < NN)
                    h1f8[(size_t)row * 256 + colb + ni * 16 + dc] = f2fp8_hw(v);
            }
#pragma unroll
            for (int m = 8; m >= 1; m >>= 1) {
                s += __shfl_xor(s, m);
                d += __shfl_xor(d, m);
            }
            if (dc == 0 && row < NN) {
                alpha_s[row * 4 + w] = s;
                alpha_d[row * 4 + w] = d;
            }
        }
    }
}

// ---------------- bucket fill (CSR column indices) ------------------------
__global__ void k_fill(const int* __restrict__ ei, int* __restrict__ cursor,
                       int* __restrict__ srcs) {
    int t = blockIdx.x * 256 + threadIdx.x;
    if (t >= ETOT) return;
    int src = (t < EE) ? ei[t] : (t - EE);
    int dst = (t < EE) ? ei[EE + t] : (t - EE);
    int p = atomicAdd(cursor + dst, 1);
    srcs[p] = src;
}

// ---------------- gather-aggregate layer 1 + softmax + bias + ELU ---------
// one wave per dst node; lane l owns channels 4l..4l+3 (head = l>>4).
// fp8 payload decoded with native cvt_pk_f32_fp8. 2-edge unroll for ILP.
__global__ void k_gather1(const int* __restrict__ indptr, const int* __restrict__ srcs,
                          const float* __restrict__ alpha_s, const float* __restrict__ alpha_d,
                          const unsigned char* __restrict__ h1f8, const float* __restrict__ b1,
                          unsigned short* __restrict__ h1o) {
    int wid = (blockIdx.x * 256 + threadIdx.x) >> 6;
    int l = threadIdx.x & 63;
    if (wid >= NN) return;
    int p0 = indptr[wid], p1 = indptr[wid + 1];
    int head = l >> 4;
    float adh = alpha_d[wid * 4 + head];
    float acc0 = 0.f, acc1 = 0.f, acc2 = 0.f, acc3 = 0.f, dsum = 0.f;
    int p = p0;
    for (; p + 1 < p1; p += 2) {
        int sA = srcs[p], sB = srcs[p + 1];
        float eA = alpha_s[sA * 4 + head] + adh;
        float eB = alpha_s[sB * 4 + head] + adh;
        unsigned int hvA = *(const unsigned int*)&h1f8[(size_t)sA * 256 + l * 4];
        unsigned int hvB = *(const unsigned int*)&h1f8[(size_t)sB * 256 + l * 4];
        eA = eA > 0.f ? eA : 0.2f * eA;
        eB = eB > 0.f ? eB : 0.2f * eB;
        float wA = __expf(eA);
        float wB = __expf(eB);
        float2v loA = __builtin_amdgcn_cvt_pk_f32_fp8(hvA, false);
        float2v hiA = __builtin_amdgcn_cvt_pk_f32_fp8(hvA, true);
        float2v loB = __builtin_amdgcn_cvt_pk_f32_fp8(hvB, false);
        float2v hiB = __builtin_amdgcn_cvt_pk_f32_fp8(hvB, true);
        dsum += wA + wB;
        acc0 += wA * loA.x + wB * loB.x;
        acc1 += wA * loA.y + wB * loB.y;
        acc2 += wA * hiA.x + wB * hiB.x;
        acc3 += wA * hiA.y + wB * hiB.y;
    }
    if (p < p1) {
        int s = srcs[p];
        float e = alpha_s[s * 4 + head] + adh;
        e = e > 0.f ? e : 0.2f * e;
        float w = __expf(e);
        unsigned int hv = *(const unsigned int*)&h1f8[(size_t)s * 256 + l * 4];
        float2v lo = __builtin_amdgcn_cvt_pk_f32_fp8(hv, false);
        float2v hi = __builtin_amdgcn_cvt_pk_f32_fp8(hv, true);
        dsum += w;
        acc0 += w * lo.x;
        acc1 += w * lo.y;
        acc2 += w * hi.x;
        acc3 += w * hi.y;
    }
    float inv = 1.0f / dsum;
    float4 bv = *(const float4*)&b1[l * 4];
    float o0 = acc0 * inv + bv.x;
    float o1 = acc1 * inv + bv.y;
    float o2 = acc2 * inv + bv.z;
    float o3 = acc3 * inv + bv.w;
    o0 = o0 > 0.f ? o0 : expm1f(o0);
    o1 = o1 > 0.f ? o1 : expm1f(o1);
    o2 = o2 > 0.f ? o2 : expm1f(o2);
    o3 = o3 > 0.f ? o3 : expm1f(o3);
    ushort4 ov;
    ov.x = f2bf(o0); ov.y = f2bf(o1); ov.z = f2bf(o2); ov.w = f2bf(o3);
    *(ushort4*)&h1o[(size_t)wid * 256 + l * 4] = ov;
}

// ---------------- GEMM2 (wave/node) + attention logits layer 2 ------------
__global__ void k_gemm2a(const unsigned short* __restrict__ h1o, const float* __restrict__ W2,
                         const float* __restrict__ as2v, const float* __restrict__ ad2v,
                         float* __restrict__ h2lin, float* __restrict__ alpha_s2,
                         float* __restrict__ alpha_d2) {
    int wid = (blockIdx.x * 256 + threadIdx.x) >> 6;
    int l = threadIdx.x & 63;
    if (wid >= NN) return;
    ushort4 hv = *(const ushort4*)&h1o[(size_t)wid * 256 + l * 4];
    float h0 = bf2f(hv.x), h1_ = bf2f(hv.y), h2 = bf2f(hv.z), h3 = bf2f(hv.w);
    float t[10];
#pragma unroll
    for (int o = 0; o < 10; ++o) {
        float4 wv = *(const float4*)&W2[o * 256 + l * 4];
        t[o] = h0 * wv.x + h1_ * wv.y + h2 * wv.z + h3 * wv.w;
    }
#pragma unroll
    for (int m = 32; m > 0; m >>= 1) {
#pragma unroll
        for (int o = 0; o < 10; ++o) t[o] += __shfl_xor(t[o], m);
    }
    if (l == 0) {
        float as = 0.f, ad = 0.f;
#pragma unroll
        for (int o = 0; o < 10; ++o) {
            h2lin[(size_t)wid * 10 + o] = t[o];
            as += t[o] * as2v[o];
            ad += t[o] * ad2v[o];
        }
        alpha_s2[wid] = as;
        alpha_d2[wid] = ad;
    }
}

// ---------------- gather layer 2 + softmax + bias + fused mean-pool -------
__global__ void k_g2pool(const int* __restrict__ indptr, const int* __restrict__ srcs,
                         const float* __restrict__ als2, const float* __restrict__ ald2,
                         const float* __restrict__ h2lin, const float* __restrict__ b2,
                         const int* __restrict__ batch, float* __restrict__ pooled) {
    int t = blockIdx.x * 256 + threadIdx.x;
    bool valid = t < NN;
    float acc[10] = {};
    int g = -1;
    if (valid) {
        int p0 = indptr[t], p1 = indptr[t + 1];
        float adt = ald2[t];
        float dsum = 0.f;
        for (int p = p0; p < p1; ++p) {
            int s = srcs[p];
            float v = als2[s] + adt;
            v = v > 0.f ? v : 0.2f * v;
            float w = __expf(v);
            dsum += w;
            const float* hr = &h2lin[(size_t)s * 10];
#pragma unroll
            for (int c = 0; c < 10; ++c) acc[c] += w * hr[c];
        }
        float inv = 1.0f / dsum;
#pragma unroll
        for (int c = 0; c < 10; ++c) acc[c] = acc[c] * inv + b2[c];
        g = batch[t];
    }
    int g0 = __shfl(g, 0);
    bool uni = __all((!valid) || (g == g0));
    if (uni) {
        if (g0 >= 0) {
#pragma unroll
            for (int m = 32; m > 0; m >>= 1) {
#pragma unroll
                for (int c = 0; c < 10; ++c) acc[c] += __shfl_xor(acc[c], m);
            }
            if ((threadIdx.x & 63) == 0) {
#pragma unroll
                for (int c = 0; c < 10; ++c) atomicAdd(pooled + g0 * 10 + c, acc[c]);
            }
        }
    } else if (valid) {
#pragma unroll
        for (int c = 0; c < 10; ++c) atomicAdd(pooled + g * 10 + c, acc[c]);
    }
}

// ---------------- mean + log_softmax --------------------------------------
__global__ void k_final(const float* __restrict__ pooled, const int* __restrict__ gcount,
                        float* __restrict__ out) {
    int g = threadIdx.x;
    if (g >= NG) return;
    float c = fmaxf((float)gcount[g], 1.0f);
    float m[10];
    float mx = -1e30f;
#pragma unroll
    for (int i = 0; i < 10; ++i) {
        m[i] = pooled[g * 10 + i] / c;
        mx = fmaxf(mx, m[i]);
    }
    float s = 0.f;
#pragma unroll
    for (int i = 0; i < 10; ++i) s += expf(m[i] - mx);
    float lse = mx + logf(s);
#pragma unroll
    for (int i = 0; i < 10; ++i) out[g * 10 + i] = m[i] - lse;
}

extern "C" void kernel_launch(void* const* d_in, const int* in_sizes, int n_in,
                              void* d_out, int out_size, void* d_ws, size_t ws_size,
                              hipStream_t stream) {
    const float* x   = (const float*)d_in[0];
    const int*   ei  = (const int*)d_in[1];
    const int*   bat = (const int*)d_in[3];
    const float* W1  = (const float*)d_in[4];
    const float* as1 = (const float*)d_in[5];
    const float* ad1 = (const float*)d_in[6];
    const float* b1  = (const float*)d_in[7];
    const float* W2  = (const float*)d_in[8];
    const float* as2 = (const float*)d_in[9];
    const float* ad2 = (const float*)d_in[10];
    const float* b2  = (const float*)d_in[11];
    float* out = (float*)d_out;

    char* ws = (char*)d_ws;
    size_t off = 0;
    auto alloc = [&](size_t bytes) -> size_t {
        size_t o = off;
        off = (off + bytes + 255) & ~(size_t)255;
        return o;
    };
    size_t o_counts = alloc((size_t)NN * 4);
    size_t o_pooled = alloc((size_t)NG * 10 * 4);
    size_t o_gcount = alloc((size_t)NG * 4);
    size_t zero_bytes = off;
    size_t o_cursor = alloc((size_t)NN * 4);
    size_t o_indptr = alloc((size_t)(NN + 1) * 4);
    size_t o_srcs   = alloc((size_t)ETOT * 4);
    size_t o_h1f8   = alloc((size_t)NN * 256);
    size_t o_h1o    = alloc((size_t)NN * 256 * 2);
    size_t o_als1   = alloc((size_t)NN * 4 * 4);
    size_t o_ald1   = alloc((size_t)NN * 4 * 4);
    size_t o_h2lin  = alloc((size_t)NN * 10 * 4);
    size_t o_als2   = alloc((size_t)NN * 4);
    size_t o_ald2   = alloc((size_t)NN * 4);
    size_t o_whi    = alloc((size_t)256 * 128 * 2);
    size_t o_wlo    = alloc((size_t)256 * 128 * 2);
    size_t o_xh     = alloc((size_t)NN * 128 * 2);
    size_t o_xl     = alloc((size_t)NN * 128 * 2);
    (void)ws_size;

    int*   counts = (int*)(ws + o_counts);
    float* pooled = (float*)(ws + o_pooled);
    int*   gcount = (int*)(ws + o_gcount);
    int*   cursor = (int*)(ws + o_cursor);
    int*   indptr = (int*)(ws + o_indptr);
    int*   srcs   = (int*)(ws + o_srcs);
    unsigned char*  h1f8 = (unsigned char*)(ws + o_h1f8);
    unsigned short* h1o  = (unsigned short*)(ws + o_h1o);
    float* als1   = (float*)(ws + o_als1);
    float* ald1   = (float*)(ws + o_ald1);
    float* h2lin  = (float*)(ws + o_h2lin);
    float* als2   = (float*)(ws + o_als2);
    float* ald2   = (float*)(ws + o_ald2);
    unsigned short* whi = (unsigned short*)(ws + o_whi);
    unsigned short* wlo = (unsigned short*)(ws + o_wlo);
    unsigned short* xh  = (unsigned short*)(ws + o_xh);
    unsigned short* xl  = (unsigned short*)(ws + o_xl);

    hipMemsetAsync(ws, 0, zero_bytes, stream);

    int gE = (ETOT + 255) / 256;
    int gW = (NN + 3) / 4;
    int gN = (NN + 255) / 256;

    k_hist<<<gE, 256, 0, stream>>>(ei, bat, counts, gcount);
    k_scan<<<1, 1024, 0, stream>>>(counts, indptr, cursor);
    k_cvtw<<<128, 256, 0, stream>>>(W1, whi, wlo);
    k_cvtx<<<(NN * 128 / 8 + 255) / 256, 256, 0, stream>>>(x, xh, xl);
    k_gemm1<<<(NN + 31) / 32, 256, 0, stream>>>(xh, xl, whi, wlo, as1, ad1, h1f8, als1, ald1);
    k_fill<<<gE, 256, 0, stream>>>(ei, cursor, srcs);
    k_gather1<<<gW, 256, 0, stream>>>(indptr, srcs, als1, ald1, h1f8, b1, h1o);
    k_gemm2a<<<gW, 256, 0, stream>>>(h1o, W2, as2, ad2, h2lin, als2, ald2);
    k_g2pool<<<gN, 256, 0, stream>>>(indptr, srcs, als2, ald2, h2lin, b2, bat, pooled);
    k_final<<<1, 64, 0, stream>>>(pooled, gcount, out);
    (void)n_in; (void)in_sizes; (void)out_size;
}

// Round 11
// 246.736 us; speedup vs baseline: 1.0881x; 1.0881x over previous
//
#include <hip/hip_runtime.h>
#include <hip/hip_bf16.h>
#include <math.h>

#define NN 50000
#define EE 500000
#define ETOT (EE + NN)
#define NG 64

typedef __attribute__((ext_vector_type(8))) short short8v;   // 8 bf16 (4 VGPRs)
typedef __attribute__((ext_vector_type(4))) float float4v;   // 4 fp32 acc
typedef __attribute__((ext_vector_type(2))) float float2v;

__device__ __forceinline__ float bf2f(unsigned short u) {
    unsigned int v = ((unsigned int)u) << 16;
    return __builtin_bit_cast(float, v);
}
__device__ __forceinline__ unsigned short f2bf(float f) {
    __hip_bfloat16 h = __float2bfloat16(f);
    return *(unsigned short*)&h;
}
// hardware fp8 e4m3 converts (gfx950 native)
__device__ __forceinline__ unsigned char f2fp8_hw(float f) {
    return (unsigned char)(__builtin_amdgcn_cvt_pk_fp8_f32(f, f, 0, false) & 0xff);
}

// ---------------- histogram of dst + per-graph node counts ----------------
__global__ void k_hist(const int* __restrict__ ei, const int* __restrict__ batch,
                       int* __restrict__ counts, int* __restrict__ gcount) {
    int t = blockIdx.x * 256 + threadIdx.x;
    if (t < ETOT) {
        int dst = (t < EE) ? ei[EE + t] : (t - EE);
        atomicAdd(counts + dst, 1);
    }
    if (t < NN) {
        int g = batch[t];
        int g0 = __shfl(g, 0);
        bool same = (g == g0);
        unsigned long long m = __ballot(same);
        if (same) {
            if ((threadIdx.x & 63) == (__ffsll((long long)m) - 1))
                atomicAdd(gcount + g0, (int)__popcll(m));
        } else {
            atomicAdd(gcount + g, 1);
        }
    }
}

// ---------------- exclusive scan counts -> indptr (+ seed cursor) ---------
__global__ void k_scan(const int* __restrict__ counts, int* __restrict__ indptr,
                       int* __restrict__ cursor) {
    __shared__ int wsum[16];
    __shared__ int carry_s;
    int tid = threadIdx.x;
    int lane = tid & 63;
    int w = tid >> 6;
    if (tid == 0) carry_s = 0;
    __syncthreads();
    for (int base = 0; base < NN; base += 4096) {
        int i = base + tid * 4;
        int v0 = 0, v1 = 0, v2 = 0, v3 = 0;
        if (i + 3 < NN) {
            int4 vv = *(const int4*)&counts[i];
            v0 = vv.x; v1 = vv.y; v2 = vv.z; v3 = vv.w;
        } else {
            if (i < NN) v0 = counts[i];
            if (i + 1 < NN) v1 = counts[i + 1];
            if (i + 2 < NN) v2 = counts[i + 2];
            if (i + 3 < NN) v3 = counts[i + 3];
        }
        int tot = v0 + v1 + v2 + v3;
        int s = tot;
#pragma unroll
        for (int off = 1; off < 64; off <<= 1) {
            int u = __shfl_up(s, off);
            if (lane >= off) s += u;
        }
        if (lane == 63) wsum[w] = s;
        __syncthreads();
        if (w == 0) {
            int t2 = (lane < 16) ? wsum[lane] : 0;
#pragma unroll
            for (int off = 1; off < 16; off <<= 1) {
                int u = __shfl_up(t2, off);
                if (lane >= off) t2 += u;
            }
            if (lane < 16) wsum[lane] = t2;
        }
        __syncthreads();
        int wpre = (w == 0) ? 0 : wsum[w - 1];
        int incl = s + wpre;
        int carry = carry_s;
        int e = carry + incl - tot;
        if (i < NN)     { indptr[i] = e;                cursor[i] = e; }
        if (i + 1 < NN) { int q = e + v0;               indptr[i+1] = q; cursor[i+1] = q; }
        if (i + 2 < NN) { int q = e + v0 + v1;          indptr[i+2] = q; cursor[i+2] = q; }
        if (i + 3 < NN) { int q = e + v0 + v1 + v2;     indptr[i+3] = q; cursor[i+3] = q; }
        __syncthreads();
        if (tid == 1023) carry_s = carry + incl;
        __syncthreads();
    }
    if (tid == 0) indptr[NN] = carry_s;
}

// ---------------- W1 -> bf16 ----------------------------------------------
__global__ void k_cvtw(const float* __restrict__ W1, unsigned short* __restrict__ wb) {
    int t = blockIdx.x * 256 + threadIdx.x;
    if (t >= 256 * 128) return;
    wb[t] = f2bf(W1[t]);
}

// ---------------- x -> bf16, 8 elems/thread -------------------------------
__global__ void k_cvtx(const float* __restrict__ x, unsigned short* __restrict__ xb) {
    int t = blockIdx.x * 256 + threadIdx.x;
    if (t >= NN * 128 / 8) return;
    float4 a = *(const float4*)&x[(size_t)t * 8];
    float4 b = *(const float4*)&x[(size_t)t * 8 + 4];
    float f[8] = {a.x, a.y, a.z, a.w, b.x, b.y, b.z, b.w};
    short8v vh;
#pragma unroll
    for (int j = 0; j < 8; ++j) vh[j] = (short)f2bf(f[j]);
    *(short8v*)&xb[(size_t)t * 8] = vh;
}

// ---------------- GEMM1 via bf16 MFMA + fused alpha logits ----------------
// h = x @ W1^T (bf16 inputs, fp32 acc); emits fp8 h1f8 + alpha_s/alpha_d.
// Wave w = head w: cols [w*64,(w+1)*64); rows [bm0,bm0+32).
// All 8 A-frags loaded up front (outstanding loads overlap one LLC latency).
__global__ __launch_bounds__(256) void k_gemm1(const unsigned short* __restrict__ xb,
                                               const unsigned short* __restrict__ wb,
                                               const float* __restrict__ att_s,
                                               const float* __restrict__ att_d,
                                               unsigned char* __restrict__ h1f8,
                                               float* __restrict__ alpha_s,
                                               float* __restrict__ alpha_d) {
    int w = threadIdx.x >> 6;
    int l = threadIdx.x & 63;
    int bm0 = blockIdx.x * 32;
    int i16 = l & 15;
    int kb = (l >> 4) * 8;
    int colb = w * 64;

    short8v a[2][4];
#pragma unroll
    for (int mi = 0; mi < 2; ++mi) {
        int r = bm0 + mi * 16 + i16;
#pragma unroll
        for (int k = 0; k < 4; ++k) {
            if (r < NN) a[mi][k] = *(const short8v*)&xb[(size_t)r * 128 + k * 32 + kb];
            else        a[mi][k] = (short8v){0,0,0,0,0,0,0,0};
        }
    }

    float4v acc[2][4];
#pragma unroll
    for (int mi = 0; mi < 2; ++mi)
#pragma unroll
        for (int ni = 0; ni < 4; ++ni)
            acc[mi][ni] = (float4v){0.f, 0.f, 0.f, 0.f};

#pragma unroll
    for (int k = 0; k < 4; ++k) {
#pragma unroll
        for (int ni = 0; ni < 4; ++ni) {
            short8v b = *(const short8v*)&wb[(size_t)(colb + ni * 16 + i16) * 128 + k * 32 + kb];
            acc[0][ni] = __builtin_amdgcn_mfma_f32_16x16x32_bf16(a[0][k], b, acc[0][ni], 0, 0, 0);
            acc[1][ni] = __builtin_amdgcn_mfma_f32_16x16x32_bf16(a[1][k], b, acc[1][ni], 0, 0, 0);
        }
    }

    // epilogue: fp8 store + fused alpha logits (head = w)
    int drb = (l >> 4) * 4;
    int dc = l & 15;
    float asw[4], adw[4];
#pragma unroll
    for (int ni = 0; ni < 4; ++ni) {
        asw[ni] = att_s[colb + ni * 16 + dc];
        adw[ni] = att_d[colb + ni * 16 + dc];
    }
#pragma unroll
    for (int mi = 0; mi < 2; ++mi) {
#pragma unroll
        for (int r = 0; r < 4; ++r) {
            int row = bm0 + mi * 16 + drb + r;
            float s = 0.f, d = 0.f;
#pragma unroll
            for (int ni = 0; ni < 4; ++ni) {
                float v = acc[mi][ni][r];
                s += v * asw[ni];
                d += v * adw[ni];
                if (row < NN)
                    h1f8[(size_t)row * 256 + colb + ni * 16 + dc] = f2fp8_hw(v);
            }
#pragma unroll
            for (int m = 8; m >= 1; m >>= 1) {
                s += __shfl_xor(s, m);
                d += __shfl_xor(d, m);
            }
            if (dc == 0 && row < NN) {
                alpha_s[row * 4 + w] = s;
                alpha_d[row * 4 + w] = d;
            }
        }
    }
}

// ---------------- bucket fill (CSR column indices) ------------------------
__global__ void k_fill(const int* __restrict__ ei, int* __restrict__ cursor,
                       int* __restrict__ srcs) {
    int t = blockIdx.x * 256 + threadIdx.x;
    if (t >= ETOT) return;
    int src = (t < EE) ? ei[t] : (t - EE);
    int dst = (t < EE) ? ei[EE + t] : (t - EE);
    int p = atomicAdd(cursor + dst, 1);
    srcs[p] = src;
}

// ---------------- gather-aggregate layer 1 + softmax + bias + ELU ---------
__global__ void k_gather1(const int* __restrict__ indptr, const int* __restrict__ srcs,
                          const float* __restrict__ alpha_s, const float* __restrict__ alpha_d,
                          const unsigned char* __restrict__ h1f8, const float* __restrict__ b1,
                          unsigned short* __restrict__ h1o) {
    int wid = (blockIdx.x * 256 + threadIdx.x) >> 6;
    int l = threadIdx.x & 63;
    if (wid >= NN) return;
    int p0 = indptr[wid], p1 = indptr[wid + 1];
    int head = l >> 4;
    float adh = alpha_d[wid * 4 + head];
    float acc0 = 0.f, acc1 = 0.f, acc2 = 0.f, acc3 = 0.f, dsum = 0.f;
    int p = p0;
    for (; p + 1 < p1; p += 2) {
        int sA = srcs[p], sB = srcs[p + 1];
        float eA = alpha_s[sA * 4 + head] + adh;
        float eB = alpha_s[sB * 4 + head] + adh;
        unsigned int hvA = *(const unsigned int*)&h1f8[(size_t)sA * 256 + l * 4];
        unsigned int hvB = *(const unsigned int*)&h1f8[(size_t)sB * 256 + l * 4];
        eA = eA > 0.f ? eA : 0.2f * eA;
        eB = eB > 0.f ? eB : 0.2f * eB;
        float wA = __expf(eA);
        float wB = __expf(eB);
        float2v loA = __builtin_amdgcn_cvt_pk_f32_fp8(hvA, false);
        float2v hiA = __builtin_amdgcn_cvt_pk_f32_fp8(hvA, true);
        float2v loB = __builtin_amdgcn_cvt_pk_f32_fp8(hvB, false);
        float2v hiB = __builtin_amdgcn_cvt_pk_f32_fp8(hvB, true);
        dsum += wA + wB;
        acc0 += wA * loA.x + wB * loB.x;
        acc1 += wA * loA.y + wB * loB.y;
        acc2 += wA * hiA.x + wB * hiB.x;
        acc3 += wA * hiA.y + wB * hiB.y;
    }
    if (p < p1) {
        int s = srcs[p];
        float e = alpha_s[s * 4 + head] + adh;
        e = e > 0.f ? e : 0.2f * e;
        float w = __expf(e);
        unsigned int hv = *(const unsigned int*)&h1f8[(size_t)s * 256 + l * 4];
        float2v lo = __builtin_amdgcn_cvt_pk_f32_fp8(hv, false);
        float2v hi = __builtin_amdgcn_cvt_pk_f32_fp8(hv, true);
        dsum += w;
        acc0 += w * lo.x;
        acc1 += w * lo.y;
        acc2 += w * hi.x;
        acc3 += w * hi.y;
    }
    float inv = 1.0f / dsum;
    float4 bv = *(const float4*)&b1[l * 4];
    float o0 = acc0 * inv + bv.x;
    float o1 = acc1 * inv + bv.y;
    float o2 = acc2 * inv + bv.z;
    float o3 = acc3 * inv + bv.w;
    o0 = o0 > 0.f ? o0 : expm1f(o0);
    o1 = o1 > 0.f ? o1 : expm1f(o1);
    o2 = o2 > 0.f ? o2 : expm1f(o2);
    o3 = o3 > 0.f ? o3 : expm1f(o3);
    ushort4 ov;
    ov.x = f2bf(o0); ov.y = f2bf(o1); ov.z = f2bf(o2); ov.w = f2bf(o3);
    *(ushort4*)&h1o[(size_t)wid * 256 + l * 4] = ov;
}

// ---------------- GEMM2 (wave/node) + attention logits layer 2 ------------
__global__ void k_gemm2a(const unsigned short* __restrict__ h1o, const float* __restrict__ W2,
                         const float* __restrict__ as2v, const float* __restrict__ ad2v,
                         float* __restrict__ h2lin, float* __restrict__ alpha_s2,
                         float* __restrict__ alpha_d2) {
    int wid = (blockIdx.x * 256 + threadIdx.x) >> 6;
    int l = threadIdx.x & 63;
    if (wid >= NN) return;
    ushort4 hv = *(const ushort4*)&h1o[(size_t)wid * 256 + l * 4];
    float h0 = bf2f(hv.x), h1_ = bf2f(hv.y), h2 = bf2f(hv.z), h3 = bf2f(hv.w);
    float t[10];
#pragma unroll
    for (int o = 0; o < 10; ++o) {
        float4 wv = *(const float4*)&W2[o * 256 + l * 4];
        t[o] = h0 * wv.x + h1_ * wv.y + h2 * wv.z + h3 * wv.w;
    }
#pragma unroll
    for (int m = 32; m > 0; m >>= 1) {
#pragma unroll
        for (int o = 0; o < 10; ++o) t[o] += __shfl_xor(t[o], m);
    }
    if (l == 0) {
        float as = 0.f, ad = 0.f;
#pragma unroll
        for (int o = 0; o < 10; ++o) {
            h2lin[(size_t)wid * 10 + o] = t[o];
            as += t[o] * as2v[o];
            ad += t[o] * ad2v[o];
        }
        alpha_s2[wid] = as;
        alpha_d2[wid] = ad;
    }
}

// ---------------- gather layer 2 + softmax + bias + fused mean-pool -------
__global__ void k_g2pool(const int* __restrict__ indptr, const int* __restrict__ srcs,
                         const float* __restrict__ als2, const float* __restrict__ ald2,
                         const float* __restrict__ h2lin, const float* __restrict__ b2,
                         const int* __restrict__ batch, float* __restrict__ pooled) {
    int t = blockIdx.x * 256 + threadIdx.x;
    bool valid = t < NN;
    float acc[10] = {};
    int g = -1;
    if (valid) {
        int p0 = indptr[t], p1 = indptr[t + 1];
        float adt = ald2[t];
        float dsum = 0.f;
        for (int p = p0; p < p1; ++p) {
            int s = srcs[p];
            float v = als2[s] + adt;
            v = v > 0.f ? v : 0.2f * v;
            float w = __expf(v);
            dsum += w;
            const float* hr = &h2lin[(size_t)s * 10];
#pragma unroll
            for (int c = 0; c < 10; ++c) acc[c] += w * hr[c];
        }
        float inv = 1.0f / dsum;
#pragma unroll
        for (int c = 0; c < 10; ++c) acc[c] = acc[c] * inv + b2[c];
        g = batch[t];
    }
    int g0 = __shfl(g, 0);
    bool uni = __all((!valid) || (g == g0));
    if (uni) {
        if (g0 >= 0) {
#pragma unroll
            for (int m = 32; m > 0; m >>= 1) {
#pragma unroll
                for (int c = 0; c < 10; ++c) acc[c] += __shfl_xor(acc[c], m);
            }
            if ((threadIdx.x & 63) == 0) {
#pragma unroll
                for (int c = 0; c < 10; ++c) atomicAdd(pooled + g0 * 10 + c, acc[c]);
            }
        }
    } else if (valid) {
#pragma unroll
        for (int c = 0; c < 10; ++c) atomicAdd(pooled + g * 10 + c, acc[c]);
    }
}

// ---------------- mean + log_softmax --------------------------------------
__global__ void k_final(const float* __restrict__ pooled, const int* __restrict__ gcount,
                        float* __restrict__ out) {
    int g = threadIdx.x;
    if (g >= NG) return;
    float c = fmaxf((float)gcount[g], 1.0f);
    float m[10];
    float mx = -1e30f;
#pragma unroll
    for (int i = 0; i < 10; ++i) {
        m[i] = pooled[g * 10 + i] / c;
        mx = fmaxf(mx, m[i]);
    }
    float s = 0.f;
#pragma unroll
    for (int i = 0; i < 10; ++i) s += expf(m[i] - mx);
    float lse = mx + logf(s);
#pragma unroll
    for (int i = 0; i < 10; ++i) out[g * 10 + i] = m[i] - lse;
}

extern "C" void kernel_launch(void* const* d_in, const int* in_sizes, int n_in,
                              void* d_out, int out_size, void* d_ws, size_t ws_size,
                              hipStream_t stream) {
    const float* x   = (const float*)d_in[0];
    const int*   ei  = (const int*)d_in[1];
    const int*   bat = (const int*)d_in[3];
    const float* W1  = (const float*)d_in[4];
    const float* as1 = (const float*)d_in[5];
    const float* ad1 = (const float*)d_in[6];
    const float* b1  = (const float*)d_in[7];
    const float* W2  = (const float*)d_in[8];
    const float* as2 = (const float*)d_in[9];
    const float* ad2 = (const float*)d_in[10];
    const float* b2  = (const float*)d_in[11];
    float* out = (float*)d_out;

    char* ws = (char*)d_ws;
    size_t off = 0;
    auto alloc = [&](size_t bytes) -> size_t {
        size_t o = off;
        off = (off + bytes + 255) & ~(size_t)255;
        return o;
    };
    size_t o_counts = alloc((size_t)NN * 4);
    size_t o_pooled = alloc((size_t)NG * 10 * 4);
    size_t o_gcount = alloc((size_t)NG * 4);
    size_t zero_bytes = off;
    size_t o_cursor = alloc((size_t)NN * 4);
    size_t o_indptr = alloc((size_t)(NN + 1) * 4);
    size_t o_srcs   = alloc((size_t)ETOT * 4);
    size_t o_h1f8   = alloc((size_t)NN * 256);
    size_t o_h1o    = alloc((size_t)NN * 256 * 2);
    size_t o_als1   = alloc((size_t)NN * 4 * 4);
    size_t o_ald1   = alloc((size_t)NN * 4 * 4);
    size_t o_h2lin  = alloc((size_t)NN * 10 * 4);
    size_t o_als2   = alloc((size_t)NN * 4);
    size_t o_ald2   = alloc((size_t)NN * 4);
    size_t o_wb     = alloc((size_t)256 * 128 * 2);
    size_t o_xb     = alloc((size_t)NN * 128 * 2);
    (void)ws_size;

    int*   counts = (int*)(ws + o_counts);
    float* pooled = (float*)(ws + o_pooled);
    int*   gcount = (int*)(ws + o_gcount);
    int*   cursor = (int*)(ws + o_cursor);
    int*   indptr = (int*)(ws + o_indptr);
    int*   srcs   = (int*)(ws + o_srcs);
    unsigned char*  h1f8 = (unsigned char*)(ws + o_h1f8);
    unsigned short* h1o  = (unsigned short*)(ws + o_h1o);
    float* als1   = (float*)(ws + o_als1);
    float* ald1   = (float*)(ws + o_ald1);
    float* h2lin  = (float*)(ws + o_h2lin);
    float* als2   = (float*)(ws + o_als2);
    float* ald2   = (float*)(ws + o_ald2);
    unsigned short* wb = (unsigned short*)(ws + o_wb);
    unsigned short* xb = (unsigned short*)(ws + o_xb);

    hipMemsetAsync(ws, 0, zero_bytes, stream);

    int gE = (ETOT + 255) / 256;
    int gW = (NN + 3) / 4;
    int gN = (NN + 255) / 256;

    k_hist<<<gE, 256, 0, stream>>>(ei, bat, counts, gcount);
    k_scan<<<1, 1024, 0, stream>>>(counts, indptr, cursor);
    k_cvtw<<<128, 256, 0, stream>>>(W1, wb);
    k_cvtx<<<(NN * 128 / 8 + 255) / 256, 256, 0, stream>>>(x, xb);
    k_gemm1<<<(NN + 31) / 32, 256, 0, stream>>>(xb, wb, as1, ad1, h1f8, als1, ald1);
    k_fill<<<gE, 256, 0, stream>>>(ei, cursor, srcs);
    k_gather1<<<gW, 256, 0, stream>>>(indptr, srcs, als1, ald1, h1f8, b1, h1o);
    k_gemm2a<<<gW, 256, 0, stream>>>(h1o, W2, as2, ad2, h2lin, als2, ald2);
    k_g2pool<<<gN, 256, 0, stream>>>(indptr, srcs, als2, ald2, h2lin, b2, bat, pooled);
    k_final<<<1, 64, 0, stream>>>(pooled, gcount, out);
    (void)n_in; (void)in_sizes; (void)out_size;
}